// Round 1
// 187.146 us; speedup vs baseline: 1.0005x; 1.0005x over previous
//
#include <hip/hip_runtime.h>

// InnerProduct: lp[r,p] = sum_f w[p,f]^2 * sum_e x[r,f,e]^2
// R=32768, F=64, E=16, P=10. Memory-bound: one coalesced pass over x (128 MiB).
constexpr int F = 64;
constexpr int E = 16;
constexpr int P = 10;

// DPP row_shr:N accumulate: x + (lane >= N ? x[lane-N] : 0), within each
// 16-lane DPP row. Pure VALU — no DS pipe, ~3 cyc vs ~25 cyc ds_swizzle.
template <int CTRL>
__device__ __forceinline__ float row_shr_acc(float x) {
    int t = __builtin_amdgcn_update_dpp(0, __float_as_int(x), CTRL,
                                        0xF, 0xF, /*bound_ctrl=*/true);
    return x + __int_as_float(t);
}

// One wave (64 lanes) per row. Row = F*E = 1024 floats = 64 lanes x 4 float4.
//
// Lane mapping (PERMUTED vs naive — coalescing is address-set based, so any
// lane->address permutation within the 1 KiB block per instruction is free):
//   g = lane & 15   -> f mod 16        (f in lane bits 0..3 => DPP-row aligned)
//   q = lane >> 4   -> e-quad 0..3     (e in lane bits 4,5; also p = q + 4j)
//   lane loads float4 index jidx = (g<<2)|q within each 64-float4 seg,
//   i.e. elements f = seg*16+g, e in [4q, 4q+4).
//
// Reduction plan:
//   stage 1 (e-combine, PRE-weight since p rides on the e-bits):
//     xor-16 via ds_swizzle + xor-32 half swap  -> 4 DS ops/row (was 8)
//   stage 2 (f-reduce over lane bits 0..3):
//     DPP row_shr 8/4/2/1 add sequence, result in lane 15 of each row
//     -> 12 VALU ops/row, ZERO DS ops (was 12 DS ops)
__global__ __launch_bounds__(256, 8) void ip_kernel(const float* __restrict__ x,
                                                    const float* __restrict__ w,
                                                    float* __restrict__ out,
                                                    int rows) {
    const int lane = threadIdx.x & 63;
    const int wave_in_block = threadIdx.x >> 6;
    const int waves_per_block = blockDim.x >> 6;
    const int wave_id = blockIdx.x * waves_per_block + wave_in_block;
    const int n_waves = gridDim.x * waves_per_block;

    const int g = lane & 15;         // f mod 16
    const int q = lane >> 4;         // e-quad; also selects p = q + 4j
    const int jidx = (g << 2) | q;   // permuted float4 index within seg

    // Preload squared weights once per wave (hoisted out of row loop).
    // wsq[j][seg] = w[q+4j, seg*16+g]^2 (0 when p >= P).
    float wsq[3][4];
#pragma unroll
    for (int j = 0; j < 3; ++j) {
        const int p = q + 4 * j;
#pragma unroll
        for (int seg = 0; seg < 4; ++seg) {
            const float wv = (p < P) ? w[p * F + seg * 16 + g] : 0.0f;
            wsq[j][seg] = wv * wv;
        }
    }

    for (int r = wave_id; r < rows; r += n_waves) {
        const float4* xrow = (const float4*)(x + (size_t)r * (F * E));
        float4 v[4];
#pragma unroll
        for (int seg = 0; seg < 4; ++seg)
            v[seg] = xrow[seg * 64 + jidx];  // permuted but fully coalesced

        float acc0 = 0.0f, acc1 = 0.0f, acc2 = 0.0f;
#pragma unroll
        for (int seg = 0; seg < 4; ++seg) {
            const float4 t = v[seg];
            float sq = t.x * t.x + t.y * t.y + t.z * t.z + t.w * t.w;
            // e-combine across lane bits 4,5 (weights independent of e):
            // xor-16 stays inside 32-lane halves -> single ds_swizzle
            sq += __int_as_float(
                __builtin_amdgcn_ds_swizzle(__float_as_int(sq), 0x401F));
            // xor-32 half exchange (permlane32_swap / bpermute, compiler's pick)
            sq += __shfl_xor(sq, 32);
            acc0 += wsq[0][seg] * sq;
            acc1 += wsq[1][seg] * sq;
            acc2 += wsq[2][seg] * sq;
        }

        // f-reduce over the 16-lane DPP row (lane bits 0..3), pure VALU.
        // row_shr:8 -> :4 -> :2 -> :1 leaves the full row sum in lane 15.
        acc0 = row_shr_acc<0x118>(acc0);
        acc1 = row_shr_acc<0x118>(acc1);
        acc2 = row_shr_acc<0x118>(acc2);
        acc0 = row_shr_acc<0x114>(acc0);
        acc1 = row_shr_acc<0x114>(acc1);
        acc2 = row_shr_acc<0x114>(acc2);
        acc0 = row_shr_acc<0x112>(acc0);
        acc1 = row_shr_acc<0x112>(acc1);
        acc2 = row_shr_acc<0x112>(acc2);
        acc0 = row_shr_acc<0x111>(acc0);
        acc1 = row_shr_acc<0x111>(acc1);
        acc2 = row_shr_acc<0x111>(acc2);

        if (g == 15) {  // lanes 15/31/47/63: one writer per e-quad row q
            float* o = out + (size_t)r * P + q;
            o[0] = acc0;              // p = q
            o[4] = acc1;              // p = q + 4
            if (q < 2) o[8] = acc2;   // p = q + 8 (only 8,9 valid)
        }
    }
}

extern "C" void kernel_launch(void* const* d_in, const int* in_sizes, int n_in,
                              void* d_out, int out_size, void* d_ws, size_t ws_size,
                              hipStream_t stream) {
    const float* x = (const float*)d_in[0];
    const float* w = (const float*)d_in[1];
    float* out = (float*)d_out;
    const int rows = in_sizes[0] / (F * E);  // 32768

    // 2048 blocks x 256 threads = 8192 waves -> 4 rows/wave grid-stride,
    // 8 blocks/CU = 32 waves/CU for max latency hiding.
    dim3 grid(2048), block(256);
    hipLaunchKernelGGL(ip_kernel, grid, block, 0, stream, x, w, out, rows);
}